// Round 1
// baseline (77.802 us; speedup 1.0000x reference)
//
#include <hip/hip_runtime.h>
#include <math.h>

#define EPSF 1e-6f

__device__ __forceinline__ float sigmoidf_(float v) { return 1.0f / (1.0f + __expf(-v)); }

// ---------------- Kernel 1: ConvDeepSet encoder ----------------
// grid: (ceil(M/16), nb), block 256 (16 n-groups x 16 m)
__global__ void enc_kernel(const float* __restrict__ x, const float* __restrict__ y,
                           const float* __restrict__ xg, const float* __restrict__ enc_sigma,
                           const float* __restrict__ gW, const float* __restrict__ gb,
                           float* __restrict__ rep_s, int nb, int npts, int M)
{
    __shared__ float red[16][16][6];  // [mi][ng][c: h0*3, h1*3]
    __shared__ float tot[16][6];
    int b = blockIdx.y;
    int mt = blockIdx.x * 16;
    int tid = threadIdx.x;
    int mi = tid & 15, ng = tid >> 4;
    int m = mt + mi;
    bool mv = (m < M);
    float inv_s[3], g[3];
    for (int c = 0; c < 3; c++) inv_s[c] = 1.0f / (__expf(enc_sigma[c]) + EPSF);
    for (int c = 0; c < 3; c++) g[c] = mv ? xg[(size_t)(b * M + m) * 3 + c] : 0.0f;
    float h0[3] = {0, 0, 0}, h1[3] = {0, 0, 0};
    for (int n = ng; n < npts; n += 16) {
        const float* xp = x + (size_t)(b * npts + n) * 3;
        const float* yp = y + (size_t)(b * npts + n) * 3;
        for (int c = 0; c < 3; c++) {
            float d = (xp[c] - g[c]) * inv_s[c];
            float w = __expf(-0.5f * d * d);
            h0[c] += w;
            h1[c] = fmaf(yp[c], w, h1[c]);
        }
    }
    for (int c = 0; c < 3; c++) { red[mi][ng][c] = h0[c]; red[mi][ng][3 + c] = h1[c]; }
    __syncthreads();
    if (tid < 96) {
        int mi2 = tid & 15, c2 = tid >> 4;
        float s = 0.0f;
        for (int k = 0; k < 16; k++) s += red[mi2][k][c2];
        tot[mi2][c2] = s;
    }
    __syncthreads();
    {
        // thread (j, mi): tid = j*16 + mi -> coalesced write along m
        int mi2 = tid & 15, j = tid >> 4;
        int m2 = mt + mi2;
        if (m2 < M) {
            float cat[6];
            for (int c = 0; c < 3; c++) {
                cat[c] = tot[mi2][c];
                cat[3 + c] = tot[mi2][3 + c] / (tot[mi2][c] + EPSF);
            }
            float r = gb[j];
            for (int i = 0; i < 6; i++) r = fmaf(cat[i], gW[i * 16 + j], r);
            rep_s[((size_t)b * 16 + j) * M + m2] = sigmoidf_(r);
        }
    }
}

// ---------------- Kernel 2: rho CNN (3 convs) + linear head ----------------
// grid: (ceil(M/64), nb), block 256
__global__ void rho_kernel(const float* __restrict__ rep_s,
                           const float* __restrict__ w1, const float* __restrict__ b1,
                           const float* __restrict__ w2, const float* __restrict__ b2,
                           const float* __restrict__ w3, const float* __restrict__ b3,
                           const float* __restrict__ linW, const float* __restrict__ linb,
                           float* __restrict__ mu, float* __restrict__ stdv,
                           int nb, int M)
{
    __shared__ float sIn[16][76];
    __shared__ float sH1[32][76];   // cols 0..71 valid, 72..75 zero pad
    __shared__ float sH2[32][68];
    __shared__ float sH3[32][64];
    int b = blockIdx.y;
    int t0 = blockIdx.x * 64;
    int tid = threadIdx.x;
    for (int idx = tid; idx < 16 * 76; idx += 256) {
        int i = idx / 76, q = idx % 76;
        int mg = t0 - 6 + q;
        sIn[i][q] = (mg >= 0 && mg < M) ? rep_s[((size_t)b * 16 + i) * M + mg] : 0.0f;
    }
    __syncthreads();
    int o = tid >> 3, qg = tid & 7;
    // conv1: 72 output cols (global col = t0 - 4 + q1)
    {
        float acc[9];
        for (int r = 0; r < 9; r++) acc[r] = b1[o];
        for (int i = 0; i < 16; i++) {
            float in13[13];
            for (int u = 0; u < 13; u++) in13[u] = sIn[i][qg * 9 + u];
            const float* wp = w1 + (o * 16 + i) * 5;
            for (int k = 0; k < 5; k++) {
                float wv = wp[k];
                for (int r = 0; r < 9; r++) acc[r] = fmaf(in13[r + k], wv, acc[r]);
            }
        }
        for (int r = 0; r < 9; r++) {
            int q1 = qg * 9 + r;
            int gc = t0 - 4 + q1;
            sH1[o][q1] = (gc >= 0 && gc < M) ? fmaxf(acc[r], 0.0f) : 0.0f;
        }
        if (qg == 7) { for (int e = 72; e < 76; e++) sH1[o][e] = 0.0f; }
    }
    __syncthreads();
    // conv2: 68 output cols (global col = t0 - 2 + q2)
    {
        float acc[9];
        for (int r = 0; r < 9; r++) acc[r] = b2[o];
        for (int i = 0; i < 32; i++) {
            float in13[13];
            for (int u = 0; u < 13; u++) in13[u] = sH1[i][qg * 9 + u];
            const float* wp = w2 + (o * 32 + i) * 5;
            for (int k = 0; k < 5; k++) {
                float wv = wp[k];
                for (int r = 0; r < 9; r++) acc[r] = fmaf(in13[r + k], wv, acc[r]);
            }
        }
        for (int r = 0; r < 9; r++) {
            int q2 = qg * 9 + r;
            if (q2 < 68) {
                int gc = t0 - 2 + q2;
                sH2[o][q2] = (gc >= 0 && gc < M) ? fmaxf(acc[r], 0.0f) : 0.0f;
            }
        }
    }
    __syncthreads();
    // conv3: 64 output cols (global col = t0 + q3), no relu
    {
        float acc[8];
        for (int r = 0; r < 8; r++) acc[r] = b3[o];
        for (int i = 0; i < 32; i++) {
            float in12[12];
            for (int u = 0; u < 12; u++) in12[u] = sH2[i][qg * 8 + u];
            const float* wp = w3 + (o * 32 + i) * 5;
            for (int k = 0; k < 5; k++) {
                float wv = wp[k];
                for (int r = 0; r < 8; r++) acc[r] = fmaf(in12[r + k], wv, acc[r]);
            }
        }
        for (int r = 0; r < 8; r++) sH3[o][qg * 8 + r] = acc[r];
    }
    __syncthreads();
    // head: h_grid = h^T @ linW + linb ; split mu / processed std
    for (int idx = tid; idx < 64 * 30; idx += 256) {
        int q = idx / 30, j = idx % 30;
        int m = t0 + q;
        if (m < M) {
            float v = linb[j];
            for (int oo = 0; oo < 32; oo++) v = fmaf(sH3[oo][q], linW[oo * 30 + j], v);
            if (j < 15) mu[((size_t)b * M + m) * 15 + j] = v;
            else        stdv[((size_t)b * M + m) * 15 + (j - 15)] = 0.1f + 0.9f * sigmoidf_(v);
        }
    }
}

// ---------------- Kernel 3: FinalLayer interpolation + output head ----------------
// grid: (ceil(ntar/16), nb), block 256 (16 m-groups x 16 t)
__global__ void final_kernel(const float* __restrict__ x_out, const float* __restrict__ xg,
                             const float* __restrict__ int_sigma, const float* __restrict__ eps,
                             const float* __restrict__ mu, const float* __restrict__ stdv,
                             const float* __restrict__ loW, const float* __restrict__ lob,
                             float* __restrict__ out, int nb, int ntar, int M)
{
    __shared__ float red[16][16][30];  // [mg][ti][A0..14, B0..14]
    __shared__ float AB[16][30];
    int b = blockIdx.y;
    int tt = blockIdx.x * 16;
    int tid = threadIdx.x;
    int ti = tid & 15, mg = tid >> 4;
    int t = tt + ti;
    bool tv = (t < ntar);
    float xt[3];
    for (int c = 0; c < 3; c++) xt[c] = tv ? x_out[((size_t)b * ntar + t) * 3 + c] : 0.0f;
    float inv_isc[15];
    for (int k = 0; k < 15; k++) inv_isc[k] = 1.0f / (__expf(int_sigma[k]) + EPSF);
    float A[15], B[15];
    for (int k = 0; k < 15; k++) { A[k] = 0.0f; B[k] = 0.0f; }
    for (int m = mg; m < M; m += 16) {
        const float* gp = xg + (size_t)(b * M + m) * 3;
        float gv[3] = {gp[0], gp[1], gp[2]};
        const float* mup = mu + ((size_t)b * M + m) * 15;
        const float* sdp = stdv + ((size_t)b * M + m) * 15;
        for (int k = 0; k < 15; k++) {
            int c = k % 3;  // k = basis*3 + c
            float d = (gv[c] - xt[c]) * inv_isc[k];
            float w = __expf(-0.5f * d * d);
            A[k] = fmaf(mup[k], w, A[k]);
            B[k] = fmaf(sdp[k], w, B[k]);
        }
    }
    for (int k = 0; k < 15; k++) { red[mg][ti][k] = A[k]; red[mg][ti][15 + k] = B[k]; }
    __syncthreads();
    for (int idx = tid; idx < 16 * 30; idx += 256) {
        int t2 = idx / 30, v = idx % 30;
        float s = 0.0f;
        for (int q = 0; q < 16; q++) s += red[q][t2][v];
        AB[t2][v] = s;
    }
    __syncthreads();
    // outputs: 16 t x 4 samples x 6 channels = 384
    for (int idx = tid; idx < 384; idx += 256) {
        int t2 = idx / 24;
        int rem = idx % 24;
        int s = rem / 6, j = rem % 6;
        int tg = tt + t2;
        if (tg < ntar) {
            float val = lob[j];
            const float* ep = eps + ((size_t)s * nb + b) * 15;
            for (int k = 0; k < 15; k++) {
                float h = fmaf(ep[k], AB[t2][15 + k], AB[t2][k]);
                val = fmaf(h, loW[k * 6 + j], val);
            }
            if (j >= 3) val = fmaxf(val, 0.0f) + log1pf(__expf(-fabsf(val)));  // softplus
            out[(((size_t)s * nb + b) * ntar + tg) * 6 + j] = val;
        }
    }
}

extern "C" void kernel_launch(void* const* d_in, const int* in_sizes, int n_in,
                              void* d_out, int out_size, void* d_ws, size_t ws_size,
                              hipStream_t stream)
{
    const float* x         = (const float*)d_in[0];
    const float* y         = (const float*)d_in[1];
    const float* x_out     = (const float*)d_in[2];
    const float* x_grid    = (const float*)d_in[3];
    const float* eps_noise = (const float*)d_in[4];
    const float* enc_sigma = (const float*)d_in[5];
    const float* gW        = (const float*)d_in[6];
    const float* gb        = (const float*)d_in[7];
    const float* w1        = (const float*)d_in[8];
    const float* b1        = (const float*)d_in[9];
    const float* w2        = (const float*)d_in[10];
    const float* b2        = (const float*)d_in[11];
    const float* w3        = (const float*)d_in[12];
    const float* b3        = (const float*)d_in[13];
    const float* linW      = (const float*)d_in[14];
    const float* linb      = (const float*)d_in[15];
    const float* int_sigma = (const float*)d_in[16];
    const float* loW       = (const float*)d_in[17];
    const float* lob       = (const float*)d_in[18];
    float* out = (float*)d_out;

    const int NS = 4, C = 3, NBASIS = 5;
    int nb   = in_sizes[4] / (NS * C * NBASIS);       // eps_noise: (NS, nb, 15)
    int npts = in_sizes[0] / (nb * C);
    int ntar = in_sizes[2] / (nb * C);
    int M    = in_sizes[3] / (nb * C);

    float* rep_s = (float*)d_ws;                       // (nb, 16, M)
    float* mu    = rep_s + (size_t)nb * 16 * M;        // (nb, M, 15)
    float* stdv  = mu + (size_t)nb * M * 15;           // (nb, M, 15)

    enc_kernel<<<dim3((M + 15) / 16, nb), 256, 0, stream>>>(
        x, y, x_grid, enc_sigma, gW, gb, rep_s, nb, npts, M);
    rho_kernel<<<dim3((M + 63) / 64, nb), 256, 0, stream>>>(
        rep_s, w1, b1, w2, b2, w3, b3, linW, linb, mu, stdv, nb, M);
    final_kernel<<<dim3((ntar + 15) / 16, nb), 256, 0, stream>>>(
        x_out, x_grid, int_sigma, eps_noise, mu, stdv, loW, lob, out, nb, ntar, M);
}